// Round 12
// baseline (3652.857 us; speedup 1.0000x reference)
//
#include <hip/hip_runtime.h>

#define N_NODES 100000
#define N_EDGES 800000
#define HDIM 100
#define LDP 112          // word-plane row stride (uints) = 448B, 64B-aligned rows
#define TSTR 104         // fp32 row stride
#define TS 108           // LDS tile row stride (words); 27 chunks of 16B per row

typedef __attribute__((ext_vector_type(8))) short bf16x8;
typedef __attribute__((ext_vector_type(4))) float f32x4;

// ---- dual-bf16 word helpers ----
__device__ inline uint packsplit(float v) {
    uint u = __float_as_uint(v);
    float r = v - __uint_as_float(u & 0xFFFF0000u);
    return (u & 0xFFFF0000u) | (__float_as_uint(r) >> 16);
}
__device__ inline float recw(uint w) {
    return __uint_as_float(w & 0xFFFF0000u) + __uint_as_float(w << 16);
}
__device__ inline uint4 relu4(uint4 a) {
    a.x &= ~(uint)((int)a.x >> 31); a.y &= ~(uint)((int)a.y >> 31);
    a.z &= ~(uint)((int)a.z >> 31); a.w &= ~(uint)((int)a.w >> 31);
    return a;
}
__device__ inline void unpack16(uint4 a, uint4 b, bf16x8& h8, bf16x8& l8) {
    union { uint u[4]; bf16x8 v; } H, L;
    H.u[0] = __builtin_amdgcn_perm(a.y, a.x, 0x07060302u);
    H.u[1] = __builtin_amdgcn_perm(a.w, a.z, 0x07060302u);
    H.u[2] = __builtin_amdgcn_perm(b.y, b.x, 0x07060302u);
    H.u[3] = __builtin_amdgcn_perm(b.w, b.z, 0x07060302u);
    L.u[0] = __builtin_amdgcn_perm(a.y, a.x, 0x05040100u);
    L.u[1] = __builtin_amdgcn_perm(a.w, a.z, 0x05040100u);
    L.u[2] = __builtin_amdgcn_perm(b.y, b.x, 0x05040100u);
    L.u[3] = __builtin_amdgcn_perm(b.w, b.z, 0x05040100u);
    h8 = H.v; l8 = L.v;
}
__device__ inline void split8(float4 a, float4 b, bf16x8& h8, bf16x8& l8) {
    float v[8] = {a.x, a.y, a.z, a.w, b.x, b.y, b.z, b.w};
    bf16x8 hh, ll;
#pragma unroll
    for (int i = 0; i < 8; ++i) {
        uint u = __float_as_uint(v[i]);
        hh[i] = (short)(u >> 16);
        float r = v[i] - __uint_as_float(u & 0xFFFF0000u);
        ll[i] = (short)(__float_as_uint(r) >> 16);
    }
    h8 = hh; l8 = ll;
}

// ---- gathered-row tile staging via global_load_lds (per-lane global src, linear LDS dest)
// 64 rows x 27 chunks x 16B; lds row stride TS=108 words. 27 wave-instructions total.
__device__ inline void stage_rows(const uint* __restrict__ base, const int* rows,
                                  uint* lds, int w, int lane)
{
    typedef __attribute__((address_space(1))) const uint GU;
    typedef __attribute__((address_space(3))) uint LU;
    for (int j = w; j < 27; j += 4) {
        int chunk = j * 64 + lane;
        int r = chunk / 27;
        int c = chunk - r * 27;
        const uint* g = base + (size_t)rows[r] * LDP + c * 4;
        __builtin_amdgcn_global_load_lds((GU*)g, (LU*)(lds + j * 256), 16, 0, 0);
    }
}

// ---------- weight packing ----------
template<int CONCAT>
__global__ __launch_bounds__(256)
void pack_k(const float* __restrict__ W, ushort* __restrict__ hi, ushort* __restrict__ lo,
            int K, int NC, int Kpad, int NCpad, int total)
{
    int idx = blockIdx.x * 256 + threadIdx.x;
    if (idx >= total) return;
    int per = NCpad * Kpad;
    int b = idx / per, rem = idx - b * per;
    int col = rem / Kpad, kv = rem - col * Kpad;
    int srck; bool valid;
    if (CONCAT) {
        int seg = kv >> 7, off = kv & 127;
        srck = seg * 100 + off;
        valid = (off < 100) && (srck < K) && (col < NC);
    } else {
        srck = kv;
        valid = (kv < K) && (col < NC);
    }
    float v = valid ? W[(long)b * K * NC + (long)srck * NC + col] : 0.f;
    uint w = packsplit(v);
    hi[idx] = (ushort)(w >> 16);
    lo[idx] = (ushort)(w & 0xFFFFu);
}

// ---------- streaming MFMA GEMM (unchanged from R11) ----------
template<int TILES, int TPW, int STEPS, int MODE, int GATHER, int AFP32, int OUTF32, int CLAMP>
__global__ __launch_bounds__(256, 2)
void gemm9_k(const uint* aP, int lda, const float* __restrict__ aF, int ldaf,
             const ushort* __restrict__ wH, const ushort* __restrict__ wL,
             const float* __restrict__ bias,
             float* __restrict__ Cf, uint* cP, int ldc,
             int M, int NC, const int* __restrict__ g0)
{
    constexpr int KPADW = STEPS * 32;
    const int tid  = threadIdx.x;
    const int lane = tid & 63;
    const int w    = tid >> 6;
    const int cl   = lane & 15;
    const int kgrp = lane >> 4;
    const long row0 = (long)blockIdx.x * 64;

    int arows[4];
#pragma unroll
    for (int rg = 0; rg < 4; ++rg) {
        long grow = row0 + rg * 16 + cl;
        int gc = (int)((grow < M) ? grow : (M - 1));
        arows[rg] = (GATHER == 3) ? g0[gc] : gc;
    }

    uint4  aw0[2][4], aw1[2][4];
    float4 af0[2][4], af1[2][4];
    bf16x8 bh[2][TPW], bl[2][TPW];
    f32x4  acc[TPW][4];
#pragma unroll
    for (int tp = 0; tp < TPW; ++tp)
#pragma unroll
        for (int rg = 0; rg < 4; ++rg) acc[tp][rg] = (f32x4){0.f, 0.f, 0.f, 0.f};

    auto loadA = [&](int st, int sl) {
        const int kk = st * 32 + kgrp * 8;
#pragma unroll
        for (int rg = 0; rg < 4; ++rg) {
            if (AFP32) {
                const float* p = aF + (size_t)arows[rg] * ldaf + kk;
                af0[sl][rg] = *(const float4*)p;
                af1[sl][rg] = *(const float4*)(p + 4);
            } else {
                bool ok = !CLAMP || ((st & 3) != 3) || (kgrp == 0);
                if (ok) {
                    const uint* p = aP + (size_t)arows[rg] * lda + kk;
                    aw0[sl][rg] = *(const uint4*)p;
                    aw1[sl][rg] = *(const uint4*)(p + 4);
                } else {
                    aw0[sl][rg] = make_uint4(0, 0, 0, 0);
                    aw1[sl][rg] = make_uint4(0, 0, 0, 0);
                }
            }
        }
    };
    auto loadB = [&](int st, int sl) {
        int kk = st * 32 + kgrp * 8;
#pragma unroll
        for (int tp = 0; tp < TPW; ++tp) {
            int colw = (w * TPW + tp) * 16 + cl;
            bh[sl][tp] = *(const bf16x8*)(wH + (size_t)colw * KPADW + kk);
            bl[sl][tp] = *(const bf16x8*)(wL + (size_t)colw * KPADW + kk);
        }
    };

    loadA(0, 0); loadB(0, 0);
    if (STEPS > 1) { loadA(1, 1); loadB(1, 1); }

#pragma unroll
    for (int st = 0; st < STEPS; ++st) {
        const int sl = st & 1;
#pragma unroll
        for (int rg = 0; rg < 4; ++rg) {
            bf16x8 aH, aL;
            if (AFP32) split8(af0[sl][rg], af1[sl][rg], aH, aL);
            else       unpack16(aw0[sl][rg], aw1[sl][rg], aH, aL);
#pragma unroll
            for (int tp = 0; tp < TPW; ++tp) {
                acc[tp][rg] = __builtin_amdgcn_mfma_f32_16x16x32_bf16(aL, bh[sl][tp], acc[tp][rg], 0, 0, 0);
                acc[tp][rg] = __builtin_amdgcn_mfma_f32_16x16x32_bf16(aH, bl[sl][tp], acc[tp][rg], 0, 0, 0);
                acc[tp][rg] = __builtin_amdgcn_mfma_f32_16x16x32_bf16(aH, bh[sl][tp], acc[tp][rg], 0, 0, 0);
            }
        }
        if (st + 2 < STEPS) { loadA(st + 2, sl); loadB(st + 2, sl); }
    }

#pragma unroll
    for (int tp = 0; tp < TPW; ++tp) {
        int col = (w * TPW + tp) * 16 + cl;
        if (col >= NC) continue;
        float bv = bias[col];
#pragma unroll
        for (int rg = 0; rg < 4; ++rg) {
#pragma unroll
            for (int i = 0; i < 4; ++i) {
                long grow = row0 + rg * 16 + kgrp * 4 + i;
                if (grow >= M) continue;
                float v = acc[tp][rg][i] + bv;
                if (MODE == 1) v = fmaxf(v, 0.f);
                long o = grow * (long)ldc + col;
                if (OUTF32) Cf[o] = v;
                else        cP[o] = packsplit(v);
            }
        }
    }
}

// ---------- fused 3+4+5: msg GEMM + relu(h[src]+..) + segmented aggregate ----------
__global__ __launch_bounds__(256, 2)
void msg_agg_k(const uint* __restrict__ eP,
               const ushort* __restrict__ wH, const ushort* __restrict__ wL,
               const float* __restrict__ bias,
               const uint* __restrict__ hP,
               const int* __restrict__ psrc, const int* __restrict__ pdst,
               float* __restrict__ aggF)
{
    __shared__ float sm[64 * TS];
    __shared__ uint  t0[64 * TS];
    __shared__ int sd[64], ssr[64];
    const int tid = threadIdx.x, lane = tid & 63, w = tid >> 6;
    const int cl = lane & 15, kgrp = lane >> 4;
    const long row0 = (long)blockIdx.x * 64;

    if (tid < 64) { sd[tid] = pdst[row0 + tid]; ssr[tid] = psrc[row0 + tid]; }
    __syncthreads();
    stage_rows(hP, ssr, t0, w, lane);        // h[src] tile -> t0 (async)

    uint4 aw0[2][4], aw1[2][4];
    bf16x8 bh[2][2], bl[2][2];
    f32x4 acc[2][4];
#pragma unroll
    for (int tp = 0; tp < 2; ++tp)
#pragma unroll
        for (int rg = 0; rg < 4; ++rg) acc[tp][rg] = (f32x4){0.f, 0.f, 0.f, 0.f};

    auto loadA = [&](int st, int sl) {
        const int kk = st * 32 + kgrp * 8;
        bool ok = (st != 3) || (kgrp == 0);
#pragma unroll
        for (int rg = 0; rg < 4; ++rg) {
            if (ok) {
                const uint* p = eP + (size_t)(row0 + rg * 16 + cl) * LDP + kk;
                aw0[sl][rg] = *(const uint4*)p;
                aw1[sl][rg] = *(const uint4*)(p + 4);
            } else {
                aw0[sl][rg] = make_uint4(0, 0, 0, 0);
                aw1[sl][rg] = make_uint4(0, 0, 0, 0);
            }
        }
    };
    auto loadB = [&](int st, int sl) {
        int kk = st * 32 + kgrp * 8;
#pragma unroll
        for (int tp = 0; tp < 2; ++tp) {
            int colw = (w * 2 + tp) * 16 + cl;
            bh[sl][tp] = *(const bf16x8*)(wH + (size_t)colw * 128 + kk);
            bl[sl][tp] = *(const bf16x8*)(wL + (size_t)colw * 128 + kk);
        }
    };

    loadA(0, 0); loadB(0, 0); loadA(1, 1); loadB(1, 1);
#pragma unroll
    for (int st = 0; st < 4; ++st) {
        const int sl = st & 1;
#pragma unroll
        for (int rg = 0; rg < 4; ++rg) {
            bf16x8 aH, aL;
            unpack16(aw0[sl][rg], aw1[sl][rg], aH, aL);
#pragma unroll
            for (int tp = 0; tp < 2; ++tp) {
                acc[tp][rg] = __builtin_amdgcn_mfma_f32_16x16x32_bf16(aL, bh[sl][tp], acc[tp][rg], 0, 0, 0);
                acc[tp][rg] = __builtin_amdgcn_mfma_f32_16x16x32_bf16(aH, bl[sl][tp], acc[tp][rg], 0, 0, 0);
                acc[tp][rg] = __builtin_amdgcn_mfma_f32_16x16x32_bf16(aH, bh[sl][tp], acc[tp][rg], 0, 0, 0);
            }
        }
        if (st + 2 < 4) { loadA(st + 2, sl); loadB(st + 2, sl); }
    }
    __syncthreads();   // staging complete (vmcnt drained)

    // msg = relu(acc + bias + h[src][col]) -> sm
#pragma unroll
    for (int tp = 0; tp < 2; ++tp) {
        int col = (w * 2 + tp) * 16 + cl;
        if (col < 100) {
            float bv = bias[col];
#pragma unroll
            for (int rg = 0; rg < 4; ++rg)
#pragma unroll
                for (int i = 0; i < 4; ++i) {
                    int row = rg * 16 + kgrp * 4 + i;
                    float hv = recw(t0[row * TS + col]);
                    sm[row * TS + col] = fmaxf(acc[tp][rg][i] + bv + hv, 0.f);
                }
        }
    }
    __syncthreads();

    // segmented reduce by dst (CSR-sorted)
    if (tid < 100) {
        const int c = tid;
        int cur = sd[0];
        float s = 0.f;
        bool first = true;
        for (int r = 0; r < 64; ++r) {
            int d = sd[r];
            if (d != cur) {
                bool contPrev = first && (row0 > 0) && (pdst[row0 - 1] == cur);
                if (contPrev) atomicAdd(&aggF[(size_t)cur * TSTR + c], s);
                else aggF[(size_t)cur * TSTR + c] = recw(hP[(size_t)cur * LDP + c]) + s;
                first = false; s = 0.f; cur = d;
            }
            s += sm[r * TS + c];
        }
        bool contPrev = first && (row0 > 0) && (pdst[row0 - 1] == cur);
        bool contNext = (row0 + 64 < N_EDGES) && (pdst[row0 + 64] == cur);
        if (contPrev || contNext) atomicAdd(&aggF[(size_t)cur * TSTR + c], s);
        else aggF[(size_t)cur * TSTR + c] = recw(hP[(size_t)cur * LDP + c]) + s;
    }
}

// ---------- fused 10+11: e += 0.5*(relu(cat@ew1+b1)@ew2+b2), h tiles staged via global_load_lds
__global__ __launch_bounds__(256, 2)
void fused_edge_k(const uint* __restrict__ hP, uint* eP,
                  const ushort* __restrict__ w1H, const ushort* __restrict__ w1L,
                  const float* __restrict__ b1v,
                  const ushort* __restrict__ w2H, const ushort* __restrict__ w2L,
                  const float* __restrict__ b2v,
                  const int* __restrict__ g0, const int* __restrict__ g1)
{
    __shared__ uint t0[64 * TS];
    __shared__ uint t1[64 * TS];
    __shared__ int sidx[64], didx[64];
    const int tid = threadIdx.x, lane = tid & 63, w = tid >> 6;
    const int cl = lane & 15, kgrp = lane >> 4;
    const long row0 = (long)blockIdx.x * 64;

    if (tid < 64) { sidx[tid] = g0[row0 + tid]; didx[tid] = g1[row0 + tid]; }
    __syncthreads();
    stage_rows(hP, sidx, t0, w, lane);
    stage_rows(hP, didx, t1, w, lane);

    uint4 aw0[2][4], aw1[2][4];
    bf16x8 bh[2][2], bl[2][2];
    f32x4 acc[2][4];
#pragma unroll
    for (int tp = 0; tp < 2; ++tp)
#pragma unroll
        for (int rg = 0; rg < 4; ++rg) acc[tp][rg] = (f32x4){0.f, 0.f, 0.f, 0.f};

    auto loadBk = [&](int kkbase, int st, int sl) {     // pass-1 B (ew1, Kpad 384)
        int kk = kkbase + st * 32 + kgrp * 8;
#pragma unroll
        for (int tp = 0; tp < 2; ++tp) {
            int colw = (w * 2 + tp) * 16 + cl;
            bh[sl][tp] = *(const bf16x8*)(w1H + (size_t)colw * 384 + kk);
            bl[sl][tp] = *(const bf16x8*)(w1L + (size_t)colw * 384 + kk);
        }
    };
    auto loadAe = [&](int st, int sl) {                 // seg2: e rows, sequential
        const int kk = st * 32 + kgrp * 8;
        bool ok = (st != 3) || (kgrp == 0);
#pragma unroll
        for (int rg = 0; rg < 4; ++rg) {
            if (ok) {
                const uint* p = eP + (size_t)(row0 + rg * 16 + cl) * LDP + kk;
                aw0[sl][rg] = *(const uint4*)p;
                aw1[sl][rg] = *(const uint4*)(p + 4);
            } else {
                aw0[sl][rg] = make_uint4(0, 0, 0, 0);
                aw1[sl][rg] = make_uint4(0, 0, 0, 0);
            }
        }
    };

    // phase A: seg2 (e), overlaps with staging
    loadAe(0, 0); loadBk(256, 0, 0); loadAe(1, 1); loadBk(256, 1, 1);
#pragma unroll
    for (int st = 0; st < 4; ++st) {
        const int sl = st & 1;
#pragma unroll
        for (int rg = 0; rg < 4; ++rg) {
            bf16x8 aH, aL;
            unpack16(aw0[sl][rg], aw1[sl][rg], aH, aL);
#pragma unroll
            for (int tp = 0; tp < 2; ++tp) {
                acc[tp][rg] = __builtin_amdgcn_mfma_f32_16x16x32_bf16(aL, bh[sl][tp], acc[tp][rg], 0, 0, 0);
                acc[tp][rg] = __builtin_amdgcn_mfma_f32_16x16x32_bf16(aH, bl[sl][tp], acc[tp][rg], 0, 0, 0);
                acc[tp][rg] = __builtin_amdgcn_mfma_f32_16x16x32_bf16(aH, bh[sl][tp], acc[tp][rg], 0, 0, 0);
            }
        }
        if (st + 2 < 4) { loadAe(st + 2, sl); loadBk(256, st + 2, sl); }
    }
    __syncthreads();    // staging complete

    // phase B: seg0 from t0 (p 0-3), seg1 from t1 (p 4-7); A via ds_read
    loadBk(0, 0, 0); loadBk(0, 1, 1);
#pragma unroll
    for (int p = 0; p < 8; ++p) {
        const int sl = p & 1;
        const uint* t = (p < 4) ? t0 : t1;
        int inseg = (p & 3) * 32 + kgrp * 8;
        bool ok = ((p & 3) != 3) || (kgrp == 0);
#pragma unroll
        for (int rg = 0; rg < 4; ++rg) {
            uint4 q0 = make_uint4(0, 0, 0, 0), q1 = make_uint4(0, 0, 0, 0);
            if (ok) {
                int ro = (rg * 16 + cl) * TS + inseg;
                q0 = *(const uint4*)&t[ro];
                q1 = *(const uint4*)&t[ro + 4];
            }
            bf16x8 aH, aL;
            unpack16(q0, q1, aH, aL);
#pragma unroll
            for (int tp = 0; tp < 2; ++tp) {
                acc[tp][rg] = __builtin_amdgcn_mfma_f32_16x16x32_bf16(aL, bh[sl][tp], acc[tp][rg], 0, 0, 0);
                acc[tp][rg] = __builtin_amdgcn_mfma_f32_16x16x32_bf16(aH, bl[sl][tp], acc[tp][rg], 0, 0, 0);
                acc[tp][rg] = __builtin_amdgcn_mfma_f32_16x16x32_bf16(aH, bh[sl][tp], acc[tp][rg], 0, 0, 0);
            }
        }
        if (p + 2 < 8) {
            int np = p + 2;
            loadBk((np < 4) ? 0 : 128, np & 3, sl);
        }
    }
    __syncthreads();

    // tmp2 -> t0 (packed words, stride TS; cols 100..107 zero)
#pragma unroll
    for (int tp = 0; tp < 2; ++tp) {
        int col = (w * 2 + tp) * 16 + cl;
        if (col < TS) {
            float bv = (col < 100) ? b1v[col] : 0.f;
#pragma unroll
            for (int rg = 0; rg < 4; ++rg)
#pragma unroll
                for (int i = 0; i < 4; ++i) {
                    int row = rg * 16 + kgrp * 4 + i;
                    uint u = 0;
                    if (col < 100) u = packsplit(fmaxf(acc[tp][rg][i] + bv, 0.f));
                    t0[row * TS + col] = u;
                }
        }
    }
    __syncthreads();

    // pass 2: acc2 = tmp2 @ ew2 (K=128 from t0)
    f32x4 acc2[2][4];
#pragma unroll
    for (int tp = 0; tp < 2; ++tp)
#pragma unroll
        for (int rg = 0; rg < 4; ++rg) acc2[tp][rg] = (f32x4){0.f, 0.f, 0.f, 0.f};
    bf16x8 ch[2][2], clo[2][2];
    auto loadB2 = [&](int st, int sl) {
        int kk = st * 32 + kgrp * 8;
#pragma unroll
        for (int tp = 0; tp < 2; ++tp) {
            int colw = (w * 2 + tp) * 16 + cl;
            ch[sl][tp]  = *(const bf16x8*)(w2H + (size_t)colw * 128 + kk);
            clo[sl][tp] = *(const bf16x8*)(w2L + (size_t)colw * 128 + kk);
        }
    };
    loadB2(0, 0); loadB2(1, 1);
#pragma unroll
    for (int st = 0; st < 4; ++st) {
        const int sl = st & 1;
#pragma unroll
        for (int rg = 0; rg < 4; ++rg) {
            int kk = st * 32 + kgrp * 8;
            uint4 q0 = make_uint4(0, 0, 0, 0), q1 = make_uint4(0, 0, 0, 0);
            if ((st != 3) || (kgrp == 0)) {
                int ro = (rg * 16 + cl) * TS + kk;
                q0 = *(const uint4*)&t0[ro];
                q1 = *(const uint4*)&t0[ro + 4];
            }
            bf16x8 aH, aL;
            unpack16(q0, q1, aH, aL);
#pragma unroll
            for (int tp = 0; tp < 2; ++tp) {
                acc2[tp][rg] = __builtin_amdgcn_mfma_f32_16x16x32_bf16(aL, ch[sl][tp], acc2[tp][rg], 0, 0, 0);
                acc2[tp][rg] = __builtin_amdgcn_mfma_f32_16x16x32_bf16(aH, clo[sl][tp], acc2[tp][rg], 0, 0, 0);
                acc2[tp][rg] = __builtin_amdgcn_mfma_f32_16x16x32_bf16(aH, ch[sl][tp], acc2[tp][rg], 0, 0, 0);
            }
        }
        if (st + 2 < 4) loadB2(st + 2, sl);
    }
#pragma unroll
    for (int tp = 0; tp < 2; ++tp) {
        int col = (w * 2 + tp) * 16 + cl;
        if (col >= 100) continue;
        float bv = b2v[col];
#pragma unroll
        for (int rg = 0; rg < 4; ++rg)
#pragma unroll
            for (int i = 0; i < 4; ++i) {
                long grow = row0 + rg * 16 + kgrp * 4 + i;
                long o = grow * (long)LDP + col;
                float v = recw(eP[o]) + 0.5f * (acc2[tp][rg][i] + bv);
                eP[o] = packsplit(v);
            }
    }
}

// ---------- fused 12+13+14 ----------
__global__ __launch_bounds__(256, 2)
void fused_final_k(const uint* __restrict__ hP, const uint* __restrict__ eP,
                   const ushort* __restrict__ m1H, const ushort* __restrict__ m1L,
                   const float* __restrict__ mb1,
                   const ushort* __restrict__ m2H, const ushort* __restrict__ m2L,
                   const float* __restrict__ mb2, const float* __restrict__ mw3,
                   const float* __restrict__ mb3,
                   const int* __restrict__ g0, const int* __restrict__ g1,
                   const int* __restrict__ eidx, float* __restrict__ out)
{
    __shared__ uint t0[64 * TS];
    __shared__ uint t1[64 * TS];
    __shared__ int sidx[64], didx[64];
    const int tid = threadIdx.x, lane = tid & 63, w = tid >> 6;
    const int cl = lane & 15, kgrp = lane >> 4;
    const long row0 = (long)blockIdx.x * 64;

    if (tid < 64) { sidx[tid] = g0[row0 + tid]; didx[tid] = g1[row0 + tid]; }
    __syncthreads();
    stage_rows(hP, sidx, t0, w, lane);
    stage_rows(hP, didx, t1, w, lane);

    uint4 aw0[2][4], aw1[2][4];
    bf16x8 bh[2], bl[2];
    f32x4 acc1[4];
#pragma unroll
    for (int rg = 0; rg < 4; ++rg) acc1[rg] = (f32x4){0.f, 0.f, 0.f, 0.f};

    auto loadBk = [&](int kkbase, int st, int sl) {
        int kk = kkbase + st * 32 + kgrp * 8;
        int colw = w * 16 + cl;
        bh[sl] = *(const bf16x8*)(m1H + (size_t)colw * 384 + kk);
        bl[sl] = *(const bf16x8*)(m1L + (size_t)colw * 384 + kk);
    };
    auto loadAe = [&](int st, int sl) {
        const int kk = st * 32 + kgrp * 8;
        bool ok = (st != 3) || (kgrp == 0);
#pragma unroll
        for (int rg = 0; rg < 4; ++rg) {
            if (ok) {
                const uint* p = eP + (size_t)(row0 + rg * 16 + cl) * LDP + kk;
                aw0[sl][rg] = *(const uint4*)p;
                aw1[sl][rg] = *(const uint4*)(p + 4);
            } else {
                aw0[sl][rg] = make_uint4(0, 0, 0, 0);
                aw1[sl][rg] = make_uint4(0, 0, 0, 0);
            }
        }
    };

    // phase A: seg2 (e, no relu)
    loadAe(0, 0); loadBk(256, 0, 0); loadAe(1, 1); loadBk(256, 1, 1);
#pragma unroll
    for (int st = 0; st < 4; ++st) {
        const int sl = st & 1;
#pragma unroll
        for (int rg = 0; rg < 4; ++rg) {
            bf16x8 aH, aL;
            unpack16(aw0[sl][rg], aw1[sl][rg], aH, aL);
            acc1[rg] = __builtin_amdgcn_mfma_f32_16x16x32_bf16(aL, bh[sl], acc1[rg], 0, 0, 0);
            acc1[rg] = __builtin_amdgcn_mfma_f32_16x16x32_bf16(aH, bl[sl], acc1[rg], 0, 0, 0);
            acc1[rg] = __builtin_amdgcn_mfma_f32_16x16x32_bf16(aH, bh[sl], acc1[rg], 0, 0, 0);
        }
        if (st + 2 < 4) { loadAe(st + 2, sl); loadBk(256, st + 2, sl); }
    }
    __syncthreads();

    // phase B: seg0/seg1 from LDS with relu on h
    loadBk(0, 0, 0); loadBk(0, 1, 1);
#pragma unroll
    for (int p = 0; p < 8; ++p) {
        const int sl = p & 1;
        const uint* t = (p < 4) ? t0 : t1;
        int inseg = (p & 3) * 32 + kgrp * 8;
        bool ok = ((p & 3) != 3) || (kgrp == 0);
#pragma unroll
        for (int rg = 0; rg < 4; ++rg) {
            uint4 q0 = make_uint4(0, 0, 0, 0), q1 = make_uint4(0, 0, 0, 0);
            if (ok) {
                int ro = (rg * 16 + cl) * TS + inseg;
                q0 = relu4(*(const uint4*)&t[ro]);
                q1 = relu4(*(const uint4*)&t[ro + 4]);
            }
            bf16x8 aH, aL;
            unpack16(q0, q1, aH, aL);
            acc1[rg] = __builtin_amdgcn_mfma_f32_16x16x32_bf16(aL, bh[sl], acc1[rg], 0, 0, 0);
            acc1[rg] = __builtin_amdgcn_mfma_f32_16x16x32_bf16(aH, bl[sl], acc1[rg], 0, 0, 0);
            acc1[rg] = __builtin_amdgcn_mfma_f32_16x16x32_bf16(aH, bh[sl], acc1[rg], 0, 0, 0);
        }
        if (p + 2 < 8) {
            int np = p + 2;
            loadBk((np < 4) ? 0 : 128, np & 3, sl);
        }
    }
    __syncthreads();

    // f1 -> t0 (stride 68 words; cols 50..67 zero)
    {
        int col = w * 16 + cl;
        float bv = (col < 50) ? mb1[col] : 0.f;
#pragma unroll
        for (int rg = 0; rg < 4; ++rg)
#pragma unroll
            for (int i = 0; i < 4; ++i) {
                int row = rg * 16 + kgrp * 4 + i;
                uint u = 0;
                if (col < 50) u = packsplit(fmaxf(acc1[rg][i] + bv, 0.f));
                t0[row * 68 + col] = u;
            }
    }
    __syncthreads();

    bf16x8 c2h[2][2], c2l[2][2];
#pragma unroll
    for (int t = 0; t < 2; ++t)
#pragma unroll
        for (int st = 0; st < 2; ++st) {
            long o = (long)(t * 16 + cl) * 64 + st * 32 + kgrp * 8;
            c2h[t][st] = *(const bf16x8*)(m2H + o);
            c2l[t][st] = *(const bf16x8*)(m2L + o);
        }
    const float bias0 = mb2[cl];
    const float bias1 = (cl + 16 < 25) ? mb2[cl + 16] : 0.f;
    const float w3a0 = mw3[cl * 2 + 0], w3a1 = mw3[cl * 2 + 1];
    const float w3b0 = (cl + 16 < 25) ? mw3[(cl + 16) * 2 + 0] : 0.f;
    const float w3b1 = (cl + 16 < 25) ? mw3[(cl + 16) * 2 + 1] : 0.f;
    const float b30 = mb3[0], b31 = mb3[1];

    const int row = w * 16 + cl;
    f32x4 a0 = (f32x4){0.f, 0.f, 0.f, 0.f}, a1 = a0;
#pragma unroll
    for (int st = 0; st < 2; ++st) {
        int kk = st * 32 + kgrp * 8;
        uint4 q0 = *(const uint4*)&t0[row * 68 + kk];
        uint4 q1 = *(const uint4*)&t0[row * 68 + kk + 4];
        bf16x8 aH, aL;
        unpack16(q0, q1, aH, aL);
        a0 = __builtin_amdgcn_mfma_f32_16x16x32_bf16(aL, c2h[0][st], a0, 0, 0, 0);
        a0 = __builtin_amdgcn_mfma_f32_16x16x32_bf16(aH, c2l[0][st], a0, 0, 0, 0);
        a0 = __builtin_amdgcn_mfma_f32_16x16x32_bf16(aH, c2h[0][st], a0, 0, 0, 0);
        a1 = __builtin_amdgcn_mfma_f32_16x16x32_bf16(aL, c2h[1][st], a1, 0, 0, 0);
        a1 = __builtin_amdgcn_mfma_f32_16x16x32_bf16(aH, c2l[1][st], a1, 0, 0, 0);
        a1 = __builtin_amdgcn_mfma_f32_16x16x32_bf16(aH, c2h[1][st], a1, 0, 0, 0);
    }
#pragma unroll
    for (int i = 0; i < 4; ++i) {
        float t0v = fmaxf(a0[i] + bias0, 0.f);
        float t1v = fmaxf(a1[i] + bias1, 0.f);
        float s0 = t0v * w3a0 + t1v * w3b0;
        float s1 = t0v * w3a1 + t1v * w3b1;
#pragma unroll
        for (int d = 1; d < 16; d <<= 1) {
            s0 += __shfl_xor(s0, d, 64);
            s1 += __shfl_xor(s1, d, 64);
        }
        if (cl == 0) {
            long grow = row0 + w * 16 + kgrp * 4 + i;
            int oe = eidx[grow];
            out[(long)oe * 2 + 0] = s0 + b30;
            out[(long)oe * 2 + 1] = s1 + b31;
        }
    }
}

// ---------- CSR build ----------
__global__ __launch_bounds__(256)
void hist_k(const int* __restrict__ dst, int* __restrict__ cnt)
{
    int e = blockIdx.x * 256 + threadIdx.x;
    if (e < N_EDGES) atomicAdd(&cnt[dst[e]], 1);
}

__global__ __launch_bounds__(1024)
void scan_k(const int* __restrict__ cnt, int* __restrict__ off)
{
    __shared__ int part[1024];
    const int t = threadIdx.x;
    const int per = (N_NODES + 1023) / 1024;
    const int base = t * per;
    int s = 0;
    for (int i = 0; i < per; ++i) {
        int n = base + i;
        if (n < N_NODES) s += cnt[n];
    }
    part[t] = s;
    __syncthreads();
    for (int d = 1; d < 1024; d <<= 1) {
        int v = (t >= d) ? part[t - d] : 0;
        __syncthreads();
        part[t] += v;
        __syncthreads();
    }
    int run = (t == 0) ? 0 : part[t - 1];
    for (int i = 0; i < per; ++i) {
        int n = base + i;
        if (n < N_NODES) { off[n] = run; run += cnt[n]; }
    }
    if (t == 1023) off[N_NODES] = run;
}

__global__ __launch_bounds__(256)
void fill_k(const int* __restrict__ dst, const int* __restrict__ off,
            int* __restrict__ pos, int* __restrict__ eidx)
{
    int e = blockIdx.x * 256 + threadIdx.x;
    if (e >= N_EDGES) return;
    int d = dst[e];
    int p = atomicAdd(&pos[d], 1);
    eidx[off[d] + p] = e;
}

__global__ __launch_bounds__(256)
void perm_k(const int* __restrict__ eidx, const int* __restrict__ src,
            const int* __restrict__ dst, int* __restrict__ psrc, int* __restrict__ pdst)
{
    int j = blockIdx.x * 256 + threadIdx.x;
    if (j >= N_EDGES) return;
    int e = eidx[j];
    psrc[j] = src[e];
    pdst[j] = dst[e];
}

// ---------- aggF = h ----------
__global__ __launch_bounds__(256)
void h2agg_k(const uint* __restrict__ hP, float* __restrict__ aggF)
{
    unsigned idx = blockIdx.x * 256u + threadIdx.x;
    if (idx >= (unsigned)(N_NODES * 26)) return;
    unsigned n = idx / 26u;
    unsigned q = (idx - n * 26u) * 4u;
    long ob = (long)n * TSTR + q;
    if (q >= 100) {
        *(float4*)&aggF[ob] = make_float4(0.f, 0.f, 0.f, 0.f);
        return;
    }
    uint4 hw = *(const uint4*)&hP[(long)n * LDP + q];
    *(float4*)&aggF[ob] = make_float4(recw(hw.x), recw(hw.y), recw(hw.z), recw(hw.w));
}

__global__ __launch_bounds__(128)
void bn_stats_k(const float* __restrict__ z, float* __restrict__ stats)
{
    int c = threadIdx.x;
    if (c >= HDIM) return;
    long rows_per = (N_NODES + gridDim.x - 1) / gridDim.x;
    long r0 = (long)blockIdx.x * rows_per;
    long r1 = r0 + rows_per; if (r1 > N_NODES) r1 = N_NODES;
    float s = 0.f, s2 = 0.f;
    for (long r = r0; r < r1; ++r) {
        float v = z[r * TSTR + c];
        s += v; s2 += v * v;
    }
    atomicAdd(&stats[c], s);
    atomicAdd(&stats[HDIM + c], s2);
}

__global__ __launch_bounds__(256)
void bn_apply_k(const float* __restrict__ z2, const float* __restrict__ stats,
                const float* __restrict__ gamma, const float* __restrict__ beta,
                uint* __restrict__ hP)
{
    unsigned idx = blockIdx.x * 256u + threadIdx.x;
    if (idx >= (unsigned)(N_NODES * 25)) return;
    unsigned n = idx / 25u;
    unsigned q = (idx - n * 25u) * 4u;
    const float invN = 1.f / N_NODES;
    long ob = (long)n * LDP + q;
    uint4 hw = *(const uint4*)&hP[ob];
    float4 zv = *(const float4*)&z2[(long)n * TSTR + q];
    float hv[4] = {recw(hw.x), recw(hw.y), recw(hw.z), recw(hw.w)};
    float zz[4] = {zv.x, zv.y, zv.z, zv.w};
    float r[4];
#pragma unroll
    for (int i = 0; i < 4; ++i) {
        unsigned c = q + i;
        float mu  = stats[c] * invN;
        float var = stats[HDIM + c] * invN - mu * mu;
        float v = (zz[i] - mu) * rsqrtf(var + 1e-5f) * gamma[c] + beta[c];
        r[i] = (hv[i] + fmaxf(v, 0.f)) * 0.5f;
    }
    *(uint4*)&hP[ob] = make_uint4(packsplit(r[0]), packsplit(r[1]), packsplit(r[2]), packsplit(r[3]));
}

static inline int gb64(long m) { return (int)((m + 63) / 64); }

extern "C" void kernel_launch(void* const* d_in, const int* in_sizes, int n_in,
                              void* d_out, int out_size, void* d_ws, size_t ws_size,
                              hipStream_t stream)
{
    const float* x         = (const float*)d_in[0];
    const int*   ei        = (const int*)  d_in[1];
    const float* edge_attr = (const float*)d_in[2];
    const float* node_w    = (const float*)d_in[3];
    const float* node_b    = (const float*)d_in[4];
    const float* edge_w    = (const float*)d_in[5];
    const float* edge_b    = (const float*)d_in[6];
    const float* lin_w     = (const float*)d_in[7];
    const float* lin_b     = (const float*)d_in[8];
    const float* w1        = (const float*)d_in[9];
    const float* b1        = (const float*)d_in[10];
    const float* w2        = (const float*)d_in[11];
    const float* b2        = (const float*)d_in[12];
    const float* gamma     = (const float*)d_in[13];
    const float* beta      = (const float*)d_in[14];
    const float* ew1       = (const float*)d_in[15];
    const float* eb1       = (const float*)d_in[16];
    const float* ew2       = (const float*)d_in[17];
    const float* eb2       = (const float*)d_in[18];
    const float* mw1       = (const float*)d_in[19];
    const float* mb1       = (const float*)d_in[20];
    const float* mw2       = (const float*)d_in[21];
    const float* mb2       = (const float*)d_in[22];
    const float* mw3       = (const float*)d_in[23];
    const float* mb3       = (const float*)d_in[24];
    float* out = (float*)d_out;

    ushort* pw = (ushort*)d_ws;
    size_t off_w = 0;
    ushort *nwH, *nwL, *ewH, *ewL, *liH, *liL, *w1H, *w1L, *w2H, *w2L,
           *e1H, *e1L, *e2H, *e2L, *m1H, *m1L, *m2H, *m2L;
    auto nextw = [&](size_t s, ushort*& H, ushort*& L) { H = pw + off_w; L = pw + off_w + s; off_w += 2 * s; };
    nextw(128 * 128,     nwH, nwL);
    nextw(128 * 64,      ewH, ewL);
    nextw(2 * 128 * 128, liH, liL);
    nextw(2 * 128 * 128, w1H, w1L);
    nextw(2 * 128 * 128, w2H, w2L);
    nextw(2 * 128 * 384, e1H, e1L);
    nextw(2 * 128 * 128, e2H, e2L);
    nextw(64 * 384,      m1H, m1L);
    nextw(32 * 64,       m2H, m2L);

    int* intb = (int*)((char*)d_ws + (2u << 20));
    int* cnt   = intb;
    int* coff  = cnt + N_NODES;
    int* pos   = coff + N_NODES + 1;
    int* eidx  = pos + N_NODES;
    int* psrc  = eidx + N_EDGES;
    int* pdst  = psrc + N_EDGES;
    float* stats = (float*)(pdst + N_EDGES);

    char* fbase = (char*)d_ws + (16u << 20);
    uint* eP = (uint*)fbase;                          // E*112 words
    uint* hP = eP + (size_t)N_EDGES * LDP;            // N*112
    uint* zP = hP + (size_t)N_NODES * LDP;            // N*112
    char* big = (char*)(zP + (size_t)N_NODES * LDP);
    float* aggF = (float*)big;                        // N*104 fp32
    float* z2   = aggF + (size_t)N_NODES * TSTR;      // N*104 fp32

    const int* srcp = ei;
    const int* dstp = ei + N_EDGES;
    dim3 blk(256);

    auto packl = [&](const float* W, ushort* H, ushort* L, int K, int NC, int Kp, int NCp, int batch, bool cc) {
        int total = batch * NCp * Kp;
        if (cc) pack_k<1><<<(total + 255) / 256, blk, 0, stream>>>(W, H, L, K, NC, Kp, NCp, total);
        else    pack_k<0><<<(total + 255) / 256, blk, 0, stream>>>(W, H, L, K, NC, Kp, NCp, total);
    };
    packl(node_w, nwH, nwL, 128, 100, 128, 128, 1, false);
    packl(edge_w, ewH, ewL,  64, 100,  64, 128, 1, false);
    packl(lin_w,  liH, liL, 100, 100, 128, 128, 2, false);
    packl(w1,     w1H, w1L, 100, 100, 128, 128, 2, false);
    packl(w2,     w2H, w2L, 100, 100, 128, 128, 2, false);
    packl(ew1,    e1H, e1L, 300, 100, 384, 128, 2, true);
    packl(ew2,    e2H, e2L, 100, 100, 128, 128, 2, false);
    packl(mw1,    m1H, m1L, 300,  50, 384,  64, 1, true);
    packl(mw2,    m2H, m2L,  50,  25,  64,  32, 1, false);

    hipMemsetAsync(cnt, 0, N_NODES * sizeof(int), stream);
    hist_k<<<(N_EDGES + 255) / 256, blk, 0, stream>>>(dstp, cnt);
    scan_k<<<1, dim3(1024), 0, stream>>>(cnt, coff);
    hipMemsetAsync(pos, 0, N_NODES * sizeof(int), stream);
    fill_k<<<(N_EDGES + 255) / 256, blk, 0, stream>>>(dstp, coff, pos, eidx);
    perm_k<<<(N_EDGES + 255) / 256, blk, 0, stream>>>(eidx, srcp, dstp, psrc, pdst);

    // 1. h = x @ node_w + node_b   (fp32 A, K=128) -> hP
    gemm9_k<8,2,4,0,0,1,0,0><<<gb64(N_NODES), blk, 0, stream>>>(
        nullptr, 0, x, 128, nwH, nwL, node_b, nullptr, hP, LDP, N_NODES, 100, nullptr);
    // 2. e[j] = edge_attr[eidx[j]] @ edge_w + edge_b -> eP
    gemm9_k<8,2,2,0,3,1,0,0><<<gb64(N_EDGES), blk, 0, stream>>>(
        nullptr, 0, edge_attr, 64, ewH, ewL, edge_b, nullptr, eP, LDP, N_EDGES, 100, eidx);

    for (int i = 0; i < 2; ++i) {
        h2agg_k<<<(N_NODES * 26 + 255) / 256, blk, 0, stream>>>(hP, aggF);
        // 3+4+5. fused msg GEMM + segmented aggregate
        msg_agg_k<<<gb64(N_EDGES), blk, 0, stream>>>(
            eP, liH + (size_t)i * 16384, liL + (size_t)i * 16384, lin_b + i * HDIM,
            hP, psrc, pdst, aggF);
        // 6. z = relu(aggF @ w1 + b1) -> zP
        gemm9_k<8,2,4,1,0,1,0,0><<<gb64(N_NODES), blk, 0, stream>>>(
            nullptr, 0, aggF, TSTR, w1H + (size_t)i * 16384, w1L + (size_t)i * 16384,
            b1 + i * HDIM, nullptr, zP, LDP, N_NODES, 100, nullptr);
        // 7. z2 = z @ w2 + b2 -> fp32
        gemm9_k<8,2,4,0,0,0,1,1><<<gb64(N_NODES), blk, 0, stream>>>(
            zP, LDP, nullptr, 0, w2H + (size_t)i * 16384, w2L + (size_t)i * 16384,
            b2 + i * HDIM, z2, nullptr, TSTR, N_NODES, 100, nullptr);
        // 8. BN stats
        hipMemsetAsync(stats, 0, 2 * HDIM * sizeof(float), stream);
        bn_stats_k<<<1024, dim3(128), 0, stream>>>(z2, stats);
        // 9. h = (h + relu(BN(z2)))/2
        bn_apply_k<<<(N_NODES * 25 + 255) / 256, blk, 0, stream>>>(
            z2, stats, gamma + i * HDIM, beta + i * HDIM, hP);
        // 10+11. fused edge update
        fused_edge_k<<<gb64(N_EDGES), blk, 0, stream>>>(
            hP, eP,
            e1H + (size_t)i * 49152, e1L + (size_t)i * 49152, eb1 + i * HDIM,
            e2H + (size_t)i * 16384, e2L + (size_t)i * 16384, eb2 + i * HDIM,
            psrc, pdst);
    }

    // 12+13+14. fused final MLP -> out[eidx]
    fused_final_k<<<gb64(N_EDGES), blk, 0, stream>>>(
        hP, eP, m1H, m1L, mb1, m2H, m2L, mb2, mw3, mb3, psrc, pdst, eidx, out);
}

// Round 13
// 3435.489 us; speedup vs baseline: 1.0633x; 1.0633x over previous
//
#include <hip/hip_runtime.h>

#define N_NODES 100000
#define N_EDGES 800000
#define HDIM 100
#define LDP 112          // word-plane row stride (uints) = 448B
#define TSTR 104         // fp32 row stride
#define TS 108           // LDS tile row stride (words)
#define PSTR 224         // PSD row stride (words): PS at 0, PD at +112
#define QSTR 128         // QSD row stride (words): QS at 0, QD at +64

typedef __attribute__((ext_vector_type(8))) short bf16x8;
typedef __attribute__((ext_vector_type(4))) float f32x4;

// ---- dual-bf16 word helpers ----
__device__ inline uint packsplit(float v) {
    uint u = __float_as_uint(v);
    float r = v - __uint_as_float(u & 0xFFFF0000u);
    return (u & 0xFFFF0000u) | (__float_as_uint(r) >> 16);
}
__device__ inline float recw(uint w) {
    return __uint_as_float(w & 0xFFFF0000u) + __uint_as_float(w << 16);
}
__device__ inline uint4 relu4(uint4 a) {
    a.x &= ~(uint)((int)a.x >> 31); a.y &= ~(uint)((int)a.y >> 31);
    a.z &= ~(uint)((int)a.z >> 31); a.w &= ~(uint)((int)a.w >> 31);
    return a;
}
__device__ inline void unpack16(uint4 a, uint4 b, bf16x8& h8, bf16x8& l8) {
    union { uint u[4]; bf16x8 v; } H, L;
    H.u[0] = __builtin_amdgcn_perm(a.y, a.x, 0x07060302u);
    H.u[1] = __builtin_amdgcn_perm(a.w, a.z, 0x07060302u);
    H.u[2] = __builtin_amdgcn_perm(b.y, b.x, 0x07060302u);
    H.u[3] = __builtin_amdgcn_perm(b.w, b.z, 0x07060302u);
    L.u[0] = __builtin_amdgcn_perm(a.y, a.x, 0x05040100u);
    L.u[1] = __builtin_amdgcn_perm(a.w, a.z, 0x05040100u);
    L.u[2] = __builtin_amdgcn_perm(b.y, b.x, 0x05040100u);
    L.u[3] = __builtin_amdgcn_perm(b.w, b.z, 0x05040100u);
    h8 = H.v; l8 = L.v;
}
__device__ inline void split8(float4 a, float4 b, bf16x8& h8, bf16x8& l8) {
    float v[8] = {a.x, a.y, a.z, a.w, b.x, b.y, b.z, b.w};
    bf16x8 hh, ll;
#pragma unroll
    for (int i = 0; i < 8; ++i) {
        uint u = __float_as_uint(v[i]);
        hh[i] = (short)(u >> 16);
        float r = v[i] - __uint_as_float(u & 0xFFFF0000u);
        ll[i] = (short)(__float_as_uint(r) >> 16);
    }
    h8 = hh; l8 = ll;
}

// ---------- weight packing: fp32 rows [krow0, krow0+K) of [b][srcK][NC] -> bf16 hi/lo transposed
__global__ __launch_bounds__(256)
void pack_k(const float* __restrict__ W, ushort* __restrict__ hi, ushort* __restrict__ lo,
            int K, int NC, int Kpad, int NCpad, int total, int krow0, int srcK)
{
    int idx = blockIdx.x * 256 + threadIdx.x;
    if (idx >= total) return;
    int per = NCpad * Kpad;
    int b = idx / per, rem = idx - b * per;
    int col = rem / Kpad, kv = rem - col * Kpad;
    bool valid = (kv < K) && (col < NC);
    float v = valid ? W[(long)b * srcK * NC + (long)(krow0 + kv) * NC + col] : 0.f;
    uint w = packsplit(v);
    hi[idx] = (ushort)(w >> 16);
    lo[idx] = (ushort)(w & 0xFFFFu);
}

// ---------- streaming MFMA GEMM (word-plane A or fp32 A), B in 2-slot regs.
// MODE: 0 store, 1 relu. GATHER: 0 plain, 3 rows via g0 (AFP32). RELUA: relu on word-A.
template<int TILES, int TPW, int STEPS, int MODE, int GATHER, int AFP32, int OUTF32, int CLAMP, int RELUA>
__global__ __launch_bounds__(256, 2)
void gemm10_k(const uint* aP, int lda, const float* __restrict__ aF, int ldaf,
              const ushort* __restrict__ wH, const ushort* __restrict__ wL,
              const float* __restrict__ bias,
              float* __restrict__ Cf, uint* cP, int ldc,
              int M, int NC, const int* __restrict__ g0)
{
    constexpr int KPADW = STEPS * 32;
    const int tid  = threadIdx.x;
    const int lane = tid & 63;
    const int w    = tid >> 6;
    const int cl   = lane & 15;
    const int kgrp = lane >> 4;
    const long row0 = (long)blockIdx.x * 64;

    int arows[4];
#pragma unroll
    for (int rg = 0; rg < 4; ++rg) {
        long grow = row0 + rg * 16 + cl;
        int gc = (int)((grow < M) ? grow : (M - 1));
        arows[rg] = (GATHER == 3) ? g0[gc] : gc;
    }

    uint4  aw0[2][4], aw1[2][4];
    float4 af0[2][4], af1[2][4];
    bf16x8 bh[2][TPW], bl[2][TPW];
    f32x4  acc[TPW][4];
#pragma unroll
    for (int tp = 0; tp < TPW; ++tp)
#pragma unroll
        for (int rg = 0; rg < 4; ++rg) acc[tp][rg] = (f32x4){0.f, 0.f, 0.f, 0.f};

    auto loadA = [&](int st, int sl) {
        const int kk = st * 32 + kgrp * 8;
#pragma unroll
        for (int rg = 0; rg < 4; ++rg) {
            if (AFP32) {
                const float* p = aF + (size_t)arows[rg] * ldaf + kk;
                af0[sl][rg] = *(const float4*)p;
                af1[sl][rg] = *(const float4*)(p + 4);
            } else {
                bool ok = !CLAMP || ((st & 3) != 3) || (kgrp == 0);
                if (ok) {
                    const uint* p = aP + (size_t)arows[rg] * lda + kk;
                    aw0[sl][rg] = *(const uint4*)p;
                    aw1[sl][rg] = *(const uint4*)(p + 4);
                } else {
                    aw0[sl][rg] = make_uint4(0, 0, 0, 0);
                    aw1[sl][rg] = make_uint4(0, 0, 0, 0);
                }
            }
        }
    };
    auto loadB = [&](int st, int sl) {
        int kk = st * 32 + kgrp * 8;
#pragma unroll
        for (int tp = 0; tp < TPW; ++tp) {
            int colw = (w * TPW + tp) * 16 + cl;
            bh[sl][tp] = *(const bf16x8*)(wH + (size_t)colw * KPADW + kk);
            bl[sl][tp] = *(const bf16x8*)(wL + (size_t)colw * KPADW + kk);
        }
    };

    loadA(0, 0); loadB(0, 0);
    if (STEPS > 1) { loadA(1, 1); loadB(1, 1); }

#pragma unroll
    for (int st = 0; st < STEPS; ++st) {
        const int sl = st & 1;
#pragma unroll
        for (int rg = 0; rg < 4; ++rg) {
            bf16x8 aH, aL;
            if (AFP32) split8(af0[sl][rg], af1[sl][rg], aH, aL);
            else {
                uint4 q0 = aw0[sl][rg], q1 = aw1[sl][rg];
                if (RELUA) { q0 = relu4(q0); q1 = relu4(q1); }
                unpack16(q0, q1, aH, aL);
            }
#pragma unroll
            for (int tp = 0; tp < TPW; ++tp) {
                acc[tp][rg] = __builtin_amdgcn_mfma_f32_16x16x32_bf16(aL, bh[sl][tp], acc[tp][rg], 0, 0, 0);
                acc[tp][rg] = __builtin_amdgcn_mfma_f32_16x16x32_bf16(aH, bl[sl][tp], acc[tp][rg], 0, 0, 0);
                acc[tp][rg] = __builtin_amdgcn_mfma_f32_16x16x32_bf16(aH, bh[sl][tp], acc[tp][rg], 0, 0, 0);
            }
        }
        if (st + 2 < STEPS) { loadA(st + 2, sl); loadB(st + 2, sl); }
    }

#pragma unroll
    for (int tp = 0; tp < TPW; ++tp) {
        int col = (w * TPW + tp) * 16 + cl;
        if (col >= NC) continue;
        float bv = bias[col];
#pragma unroll
        for (int rg = 0; rg < 4; ++rg) {
#pragma unroll
            for (int i = 0; i < 4; ++i) {
                long grow = row0 + rg * 16 + kgrp * 4 + i;
                if (grow >= M) continue;
                float v = acc[tp][rg][i] + bv;
                if (MODE == 1) v = fmaxf(v, 0.f);
                long o = grow * (long)ldc + col;
                if (OUTF32) Cf[o] = v;
                else        cP[o] = packsplit(v);
            }
        }
    }
}

// ---------- fused 3+4+5: msg = relu(e@lin + b + h[src]) -> segmented sum by dst -> aggF
// h[src] added in EPILOGUE (coalesced 64B per 16 lanes), no staging, no gathered MFMA-A.
__global__ __launch_bounds__(256, 2)
void msg_agg_k(const uint* __restrict__ eP,
               const ushort* __restrict__ wH, const ushort* __restrict__ wL,
               const float* __restrict__ bias,
               const uint* __restrict__ hP,
               const int* __restrict__ psrc, const int* __restrict__ pdst,
               float* __restrict__ aggF)
{
    __shared__ float sm[64 * TS];
    __shared__ int sd[64], ssr[64];
    const int tid = threadIdx.x, lane = tid & 63, w = tid >> 6;
    const int cl = lane & 15, kgrp = lane >> 4;
    const long row0 = (long)blockIdx.x * 64;

    if (tid < 64) { sd[tid] = pdst[row0 + tid]; ssr[tid] = psrc[row0 + tid]; }
    __syncthreads();

    uint4 aw0[2][4], aw1[2][4];
    bf16x8 bh[2][2], bl[2][2];
    f32x4 acc[2][4];
#pragma unroll
    for (int tp = 0; tp < 2; ++tp)
#pragma unroll
        for (int rg = 0; rg < 4; ++rg) acc[tp][rg] = (f32x4){0.f, 0.f, 0.f, 0.f};

    auto loadA = [&](int st, int sl) {
        const int kk = st * 32 + kgrp * 8;
        bool ok = (st != 3) || (kgrp == 0);
#pragma unroll
        for (int rg = 0; rg < 4; ++rg) {
            if (ok) {
                const uint* p = eP + (size_t)(row0 + rg * 16 + cl) * LDP + kk;
                aw0[sl][rg] = *(const uint4*)p;
                aw1[sl][rg] = *(const uint4*)(p + 4);
            } else {
                aw0[sl][rg] = make_uint4(0, 0, 0, 0);
                aw1[sl][rg] = make_uint4(0, 0, 0, 0);
            }
        }
    };
    auto loadB = [&](int st, int sl) {
        int kk = st * 32 + kgrp * 8;
#pragma unroll
        for (int tp = 0; tp < 2; ++tp) {
            int colw = (w * 2 + tp) * 16 + cl;
            bh[sl][tp] = *(const bf16x8*)(wH + (size_t)colw * 128 + kk);
            bl[sl][tp] = *(const bf16x8*)(wL + (size_t)colw * 128 + kk);
        }
    };

    loadA(0, 0); loadB(0, 0); loadA(1, 1); loadB(1, 1);
#pragma unroll
    for (int st = 0; st < 4; ++st) {
        const int sl = st & 1;
#pragma unroll
        for (int rg = 0; rg < 4; ++rg) {
            bf16x8 aH, aL;
            unpack16(aw0[sl][rg], aw1[sl][rg], aH, aL);
#pragma unroll
            for (int tp = 0; tp < 2; ++tp) {
                acc[tp][rg] = __builtin_amdgcn_mfma_f32_16x16x32_bf16(aL, bh[sl][tp], acc[tp][rg], 0, 0, 0);
                acc[tp][rg] = __builtin_amdgcn_mfma_f32_16x16x32_bf16(aH, bl[sl][tp], acc[tp][rg], 0, 0, 0);
                acc[tp][rg] = __builtin_amdgcn_mfma_f32_16x16x32_bf16(aH, bh[sl][tp], acc[tp][rg], 0, 0, 0);
            }
        }
        if (st + 2 < 4) { loadA(st + 2, sl); loadB(st + 2, sl); }
    }

    // epilogue: msg = relu(acc + bias + h[src][col]) -> sm (coalesced gather-add)
#pragma unroll
    for (int tp = 0; tp < 2; ++tp) {
        int col = (w * 2 + tp) * 16 + cl;
        if (col < 100) {
            float bv = bias[col];
#pragma unroll
            for (int rg = 0; rg < 4; ++rg)
#pragma unroll
                for (int i = 0; i < 4; ++i) {
                    int row = rg * 16 + kgrp * 4 + i;
                    float hv = recw(hP[(size_t)ssr[row] * LDP + col]);
                    sm[row * TS + col] = fmaxf(acc[tp][rg][i] + bv + hv, 0.f);
                }
        }
    }
    __syncthreads();

    // segmented reduce by dst (CSR-sorted)
    if (tid < 100) {
        const int c = tid;
        int cur = sd[0];
        float s = 0.f;
        bool first = true;
        for (int r = 0; r < 64; ++r) {
            int d = sd[r];
            if (d != cur) {
                bool contPrev = first && (row0 > 0) && (pdst[row0 - 1] == cur);
                if (contPrev) atomicAdd(&aggF[(size_t)cur * TSTR + c], s);
                else aggF[(size_t)cur * TSTR + c] = recw(hP[(size_t)cur * LDP + c]) + s;
                first = false; s = 0.f; cur = d;
            }
            s += sm[r * TS + c];
        }
        bool contPrev = first && (row0 > 0) && (pdst[row0 - 1] == cur);
        bool contNext = (row0 + 64 < N_EDGES) && (pdst[row0 + 64] == cur);
        if (contPrev || contNext) atomicAdd(&aggF[(size_t)cur * TSTR + c], s);
        else aggF[(size_t)cur * TSTR + c] = recw(hP[(size_t)cur * LDP + c]) + s;
    }
}

// ---------- fused 10+11: tmp2 = relu(e@We + b1 + PS[src] + PD[dst]); e += 0.5*(tmp2@ew2 + b2)
__global__ __launch_bounds__(256, 2)
void fused_edge_k(uint* eP, const uint* __restrict__ PSD,
                  const ushort* __restrict__ weH, const ushort* __restrict__ weL,
                  const float* __restrict__ b1v,
                  const ushort* __restrict__ w2H, const ushort* __restrict__ w2L,
                  const float* __restrict__ b2v,
                  const int* __restrict__ g0, const int* __restrict__ g1)
{
    __shared__ uint t0[64 * TS];
    __shared__ int ssr[64], sdd[64];
    const int tid = threadIdx.x, lane = tid & 63, w = tid >> 6;
    const int cl = lane & 15, kgrp = lane >> 4;
    const long row0 = (long)blockIdx.x * 64;

    if (tid < 64) { ssr[tid] = g0[row0 + tid]; sdd[tid] = g1[row0 + tid]; }
    __syncthreads();

    uint4 aw0[2][4], aw1[2][4];
    bf16x8 bh[2][2], bl[2][2];
    f32x4 acc[2][4];
#pragma unroll
    for (int tp = 0; tp < 2; ++tp)
#pragma unroll
        for (int rg = 0; rg < 4; ++rg) acc[tp][rg] = (f32x4){0.f, 0.f, 0.f, 0.f};

    auto loadA = [&](int st, int sl) {
        const int kk = st * 32 + kgrp * 8;
        bool ok = (st != 3) || (kgrp == 0);
#pragma unroll
        for (int rg = 0; rg < 4; ++rg) {
            if (ok) {
                const uint* p = eP + (size_t)(row0 + rg * 16 + cl) * LDP + kk;
                aw0[sl][rg] = *(const uint4*)p;
                aw1[sl][rg] = *(const uint4*)(p + 4);
            } else {
                aw0[sl][rg] = make_uint4(0, 0, 0, 0);
                aw1[sl][rg] = make_uint4(0, 0, 0, 0);
            }
        }
    };
    auto loadB1 = [&](int st, int sl) {
        int kk = st * 32 + kgrp * 8;
#pragma unroll
        for (int tp = 0; tp < 2; ++tp) {
            int colw = (w * 2 + tp) * 16 + cl;
            bh[sl][tp] = *(const bf16x8*)(weH + (size_t)colw * 128 + kk);
            bl[sl][tp] = *(const bf16x8*)(weL + (size_t)colw * 128 + kk);
        }
    };

    // pass 1: acc = e @ We (K=128, sequential rows)
    loadA(0, 0); loadB1(0, 0); loadA(1, 1); loadB1(1, 1);
#pragma unroll
    for (int st = 0; st < 4; ++st) {
        const int sl = st & 1;
#pragma unroll
        for (int rg = 0; rg < 4; ++rg) {
            bf16x8 aH, aL;
            unpack16(aw0[sl][rg], aw1[sl][rg], aH, aL);
#pragma unroll
            for (int tp = 0; tp < 2; ++tp) {
                acc[tp][rg] = __builtin_amdgcn_mfma_f32_16x16x32_bf16(aL, bh[sl][tp], acc[tp][rg], 0, 0, 0);
                acc[tp][rg] = __builtin_amdgcn_mfma_f32_16x16x32_bf16(aH, bl[sl][tp], acc[tp][rg], 0, 0, 0);
                acc[tp][rg] = __builtin_amdgcn_mfma_f32_16x16x32_bf16(aH, bh[sl][tp], acc[tp][rg], 0, 0, 0);
            }
        }
        if (st + 2 < 4) { loadA(st + 2, sl); loadB1(st + 2, sl); }
    }

    // epilogue 1: tmp2 = relu(acc + b1 + PS[src] + PD[dst]) -> t0 (coalesced gather-adds)
#pragma unroll
    for (int tp = 0; tp < 2; ++tp) {
        int col = (w * 2 + tp) * 16 + cl;
        if (col < TS) {
            float bv = (col < 100) ? b1v[col] : 0.f;
#pragma unroll
            for (int rg = 0; rg < 4; ++rg)
#pragma unroll
                for (int i = 0; i < 4; ++i) {
                    int row = rg * 16 + kgrp * 4 + i;
                    uint u = 0;
                    if (col < 100) {
                        float ps = recw(PSD[(size_t)ssr[row] * PSTR + col]);
                        float pd = recw(PSD[(size_t)sdd[row] * PSTR + 112 + col]);
                        u = packsplit(fmaxf(acc[tp][rg][i] + bv + ps + pd, 0.f));
                    }
                    t0[row * TS + col] = u;
                }
        }
    }
    __syncthreads();

    // pass 2: acc2 = tmp2 @ ew2 (K=128 from LDS)
    f32x4 acc2[2][4];
#pragma unroll
    for (int tp = 0; tp < 2; ++tp)
#pragma unroll
        for (int rg = 0; rg < 4; ++rg) acc2[tp][rg] = (f32x4){0.f, 0.f, 0.f, 0.f};
    bf16x8 ch[2][2], clo[2][2];
    auto loadB2 = [&](int st, int sl) {
        int kk = st * 32 + kgrp * 8;
#pragma unroll
        for (int tp = 0; tp < 2; ++tp) {
            int colw = (w * 2 + tp) * 16 + cl;
            ch[sl][tp]  = *(const bf16x8*)(w2H + (size_t)colw * 128 + kk);
            clo[sl][tp] = *(const bf16x8*)(w2L + (size_t)colw * 128 + kk);
        }
    };
    loadB2(0, 0); loadB2(1, 1);
#pragma unroll
    for (int st = 0; st < 4; ++st) {
        const int sl = st & 1;
#pragma unroll
        for (int rg = 0; rg < 4; ++rg) {
            int kk = st * 32 + kgrp * 8;
            uint4 q0 = make_uint4(0, 0, 0, 0), q1 = make_uint4(0, 0, 0, 0);
            if ((st != 3) || (kgrp == 0)) {
                int ro = (rg * 16 + cl) * TS + kk;
                q0 = *(const uint4*)&t0[ro];
                q1 = *(const uint4*)&t0[ro + 4];
            }
            bf16x8 aH, aL;
            unpack16(q0, q1, aH, aL);
#pragma unroll
            for (int tp = 0; tp < 2; ++tp) {
                acc2[tp][rg] = __builtin_amdgcn_mfma_f32_16x16x32_bf16(aL, ch[sl][tp], acc2[tp][rg], 0, 0, 0);
                acc2[tp][rg] = __builtin_amdgcn_mfma_f32_16x16x32_bf16(aH, clo[sl][tp], acc2[tp][rg], 0, 0, 0);
                acc2[tp][rg] = __builtin_amdgcn_mfma_f32_16x16x32_bf16(aH, ch[sl][tp], acc2[tp][rg], 0, 0, 0);
            }
        }
        if (st + 2 < 4) loadB2(st + 2, sl);
    }
#pragma unroll
    for (int tp = 0; tp < 2; ++tp) {
        int col = (w * 2 + tp) * 16 + cl;
        if (col >= 100) continue;
        float bv = b2v[col];
#pragma unroll
        for (int rg = 0; rg < 4; ++rg)
#pragma unroll
            for (int i = 0; i < 4; ++i) {
                long grow = row0 + rg * 16 + kgrp * 4 + i;
                long o = grow * (long)LDP + col;
                float v = recw(eP[o]) + 0.5f * (acc2[tp][rg][i] + bv);
                eP[o] = packsplit(v);
            }
    }
}

// ---------- fused 12+13+14: f1 = relu(e@Me + mb1 + QS[src] + QD[dst]) -> MLP -> out[eidx]
__global__ __launch_bounds__(256, 2)
void fused_final_k(const uint* __restrict__ eP, const uint* __restrict__ QSD,
                   const ushort* __restrict__ meH, const ushort* __restrict__ meL,
                   const float* __restrict__ mb1,
                   const ushort* __restrict__ m2H, const ushort* __restrict__ m2L,
                   const float* __restrict__ mb2, const float* __restrict__ mw3,
                   const float* __restrict__ mb3,
                   const int* __restrict__ g0, const int* __restrict__ g1,
                   const int* __restrict__ eidx, float* __restrict__ out)
{
    __shared__ uint t0[64 * 68];
    __shared__ int ssr[64], sdd[64];
    const int tid = threadIdx.x, lane = tid & 63, w = tid >> 6;
    const int cl = lane & 15, kgrp = lane >> 4;
    const long row0 = (long)blockIdx.x * 64;

    if (tid < 64) { ssr[tid] = g0[row0 + tid]; sdd[tid] = g1[row0 + tid]; }
    __syncthreads();

    uint4 aw0[2][4], aw1[2][4];
    bf16x8 bh[2], bl[2];
    f32x4 acc1[4];
#pragma unroll
    for (int rg = 0; rg < 4; ++rg) acc1[rg] = (f32x4){0.f, 0.f, 0.f, 0.f};

    auto loadA = [&](int st, int sl) {
        const int kk = st * 32 + kgrp * 8;
        bool ok = (st != 3) || (kgrp == 0);
#pragma unroll
        for (int rg = 0; rg < 4; ++rg) {
            if (ok) {
                const uint* p = eP + (size_t)(row0 + rg * 16 + cl) * LDP + kk;
                aw0[sl][rg] = *(const uint4*)p;
                aw1[sl][rg] = *(const uint4*)(p + 4);
            } else {
                aw0[sl][rg] = make_uint4(0, 0, 0, 0);
                aw1[sl][rg] = make_uint4(0, 0, 0, 0);
            }
        }
    };
    auto loadB1 = [&](int st, int sl) {
        int kk = st * 32 + kgrp * 8;
        int colw = w * 16 + cl;
        bh[sl] = *(const bf16x8*)(meH + (size_t)colw * 128 + kk);
        bl[sl] = *(const bf16x8*)(meL + (size_t)colw * 128 + kk);
    };

    // pass 1: acc1 = e @ Me (K=128, NC=50, 1 tile/wave)
    loadA(0, 0); loadB1(0, 0); loadA(1, 1); loadB1(1, 1);
#pragma unroll
    for (int st = 0; st < 4; ++st) {
        const int sl = st & 1;
#pragma unroll
        for (int rg = 0; rg < 4; ++rg) {
            bf16x8 aH, aL;
            unpack16(aw0[sl][rg], aw1[sl][rg], aH, aL);
            acc1[rg] = __builtin_amdgcn_mfma_f32_16x16x32_bf16(aL, bh[sl], acc1[rg], 0, 0, 0);
            acc1[rg] = __builtin_amdgcn_mfma_f32_16x16x32_bf16(aH, bl[sl], acc1[rg], 0, 0, 0);
            acc1[rg] = __builtin_amdgcn_mfma_f32_16x16x32_bf16(aH, bh[sl], acc1[rg], 0, 0, 0);
        }
        if (st + 2 < 4) { loadA(st + 2, sl); loadB1(st + 2, sl); }
    }

    // epilogue 1: f1 = relu(acc1 + mb1 + QS[src] + QD[dst]) -> t0 (stride 68)
    {
        int col = w * 16 + cl;
        float bv = (col < 50) ? mb1[col] : 0.f;
#pragma unroll
        for (int rg = 0; rg < 4; ++rg)
#pragma unroll
            for (int i = 0; i < 4; ++i) {
                int row = rg * 16 + kgrp * 4 + i;
                uint u = 0;
                if (col < 50) {
                    float qs = recw(QSD[(size_t)ssr[row] * QSTR + col]);
                    float qd = recw(QSD[(size_t)sdd[row] * QSTR + 64 + col]);
                    u = packsplit(fmaxf(acc1[rg][i] + bv + qs + qd, 0.f));
                }
                t0[row * 68 + col] = u;
            }
    }
    __syncthreads();

    // pass 2: out = relu(f1@mw2 + mb2) @ mw3 + mb3
    bf16x8 c2h[2][2], c2l[2][2];
#pragma unroll
    for (int t = 0; t < 2; ++t)
#pragma unroll
        for (int st = 0; st < 2; ++st) {
            long o = (long)(t * 16 + cl) * 64 + st * 32 + kgrp * 8;
            c2h[t][st] = *(const bf16x8*)(m2H + o);
            c2l[t][st] = *(const bf16x8*)(m2L + o);
        }
    const float bias0 = mb2[cl];
    const float bias1 = (cl + 16 < 25) ? mb2[cl + 16] : 0.f;
    const float w3a0 = mw3[cl * 2 + 0], w3a1 = mw3[cl * 2 + 1];
    const float w3b0 = (cl + 16 < 25) ? mw3[(cl + 16) * 2 + 0] : 0.f;
    const float w3b1 = (cl + 16 < 25) ? mw3[(cl + 16) * 2 + 1] : 0.f;
    const float b30 = mb3[0], b31 = mb3[1];

    const int row = w * 16 + cl;
    f32x4 a0 = (f32x4){0.f, 0.f, 0.f, 0.f}, a1 = a0;
#pragma unroll
    for (int st = 0; st < 2; ++st) {
        int kk = st * 32 + kgrp * 8;
        uint4 q0 = *(const uint4*)&t0[row * 68 + kk];
        uint4 q1 = *(const uint4*)&t0[row * 68 + kk + 4];
        bf16x8 aH, aL;
        unpack16(q0, q1, aH, aL);
        a0 = __builtin_amdgcn_mfma_f32_16x16x32_bf16(aL, c2h[0][st], a0, 0, 0, 0);
        a0 = __builtin_amdgcn_mfma_f32_16x16x32_bf16(aH, c2l[0][st], a0, 0, 0, 0);
        a0 = __builtin_amdgcn_mfma_f32_16x16x32_bf16(aH, c2h[0][st], a0, 0, 0, 0);
        a1 = __builtin_amdgcn_mfma_f32_16x16x32_bf16(aL, c2h[1][st], a1, 0, 0, 0);
        a1 = __builtin_amdgcn_mfma_f32_16x16x32_bf16(aH, c2l[1][st], a1, 0, 0, 0);
        a1 = __builtin_amdgcn_mfma_f32_16x16x32_bf16(aH, c2h[1][st], a1, 0, 0, 0);
    }
#pragma unroll
    for (int i = 0; i < 4; ++i) {
        float t0v = fmaxf(a0[i] + bias0, 0.f);
        float t1v = fmaxf(a1[i] + bias1, 0.f);
        float s0 = t0v * w3a0 + t1v * w3b0;
        float s1 = t0v * w3a1 + t1v * w3b1;
#pragma unroll
        for (int d = 1; d < 16; d <<= 1) {
            s0 += __shfl_xor(s0, d, 64);
            s1 += __shfl_xor(s1, d, 64);
        }
        if (cl == 0) {
            long grow = row0 + w * 16 + kgrp * 4 + i;
            int oe = eidx[grow];
            out[(long)oe * 2 + 0] = s0 + b30;
            out[(long)oe * 2 + 1] = s1 + b31;
        }
    }
}

// ---------- CSR build ----------
__global__ __launch_bounds__(256)
void hist_k(const int* __restrict__ dst, int* __restrict__ cnt)
{
    int e = blockIdx.x * 256 + threadIdx.x;
    if (e < N_EDGES) atomicAdd(&cnt[dst[e]], 1);
}

__global__ __launch_bounds__(1024)
void scan_k(const int* __restrict__ cnt, int* __restrict__ off)
{
    __shared__ int part[1024];
    const int t = threadIdx.x;
    const int per = (N_NODES + 1023) / 1024;
    const int base = t * per;
    int s = 0;
    for (int i = 0; i < per; ++i) {
        int n = base + i;
        if (n < N_NODES) s += cnt[n];
    }
    part[t] = s;
    __syncthreads();
    for (int d = 1; d < 1024; d <<= 1) {
        int v = (t >= d) ? part[t - d] : 0;
        __syncthreads();
        part[t] += v;
        __syncthreads();
    }
    int run = (t == 0) ? 0 : part[t - 1];
    for (int i = 0; i < per; ++i) {
        int n = base + i;
        if (n < N_NODES) { off[n] = run; run += cnt[n]; }
    }
    if (t == 1023) off[N_NODES] = run;
}

__global__ __launch_bounds__(256)
void fill_k(const int* __restrict__ dst, const int* __restrict__ off,
            int* __restrict__ pos, int* __restrict__ eidx)
{
    int e = blockIdx.x * 256 + threadIdx.x;
    if (e >= N_EDGES) return;
    int d = dst[e];
    int p = atomicAdd(&pos[d], 1);
    eidx[off[d] + p] = e;
}

__global__ __launch_bounds__(256)
void perm_k(const int* __restrict__ eidx, const int* __restrict__ src,
            const int* __restrict__ dst, int* __restrict__ psrc, int* __restrict__ pdst)
{
    int j = blockIdx.x * 256 + threadIdx.x;
    if (j >= N_EDGES) return;
    int e = eidx[j];
    psrc[j] = src[e];
    pdst[j] = dst[e];
}

// ---------- aggF = h ----------
__global__ __launch_bounds__(256)
void h2agg_k(const uint* __restrict__ hP, float* __restrict__ aggF)
{
    unsigned idx = blockIdx.x * 256u + threadIdx.x;
    if (idx >= (unsigned)(N_NODES * 26)) return;
    unsigned n = idx / 26u;
    unsigned q = (idx - n * 26u) * 4u;
    long ob = (long)n * TSTR + q;
    if (q >= 100) {
        *(float4*)&aggF[ob] = make_float4(0.f, 0.f, 0.f, 0.f);
        return;
    }
    uint4 hw = *(const uint4*)&hP[(long)n * LDP + q];
    *(float4*)&aggF[ob] = make_float4(recw(hw.x), recw(hw.y), recw(hw.z), recw(hw.w));
}

__global__ __launch_bounds__(128)
void bn_stats_k(const float* __restrict__ z, float* __restrict__ stats)
{
    int c = threadIdx.x;
    if (c >= HDIM) return;
    long rows_per = (N_NODES + gridDim.x - 1) / gridDim.x;
    long r0 = (long)blockIdx.x * rows_per;
    long r1 = r0 + rows_per; if (r1 > N_NODES) r1 = N_NODES;
    float s = 0.f, s2 = 0.f;
    for (long r = r0; r < r1; ++r) {
        float v = z[r * TSTR + c];
        s += v; s2 += v * v;
    }
    atomicAdd(&stats[c], s);
    atomicAdd(&stats[HDIM + c], s2);
}

__global__ __launch_bounds__(256)
void bn_apply_k(const float* __restrict__ z2, const float* __restrict__ stats,
                const float* __restrict__ gamma, const float* __restrict__ beta,
                uint* __restrict__ hP)
{
    unsigned idx = blockIdx.x * 256u + threadIdx.x;
    if (idx >= (unsigned)(N_NODES * 25)) return;
    unsigned n = idx / 25u;
    unsigned q = (idx - n * 25u) * 4u;
    const float invN = 1.f / N_NODES;
    long ob = (long)n * LDP + q;
    uint4 hw = *(const uint4*)&hP[ob];
    float4 zv = *(const float4*)&z2[(long)n * TSTR + q];
    float hv[4] = {recw(hw.x), recw(hw.y), recw(hw.z), recw(hw.w)};
    float zz[4] = {zv.x, zv.y, zv.z, zv.w};
    float r[4];
#pragma unroll
    for (int i = 0; i < 4; ++i) {
        unsigned c = q + i;
        float mu  = stats[c] * invN;
        float var = stats[HDIM + c] * invN - mu * mu;
        float v = (zz[i] - mu) * rsqrtf(var + 1e-5f) * gamma[c] + beta[c];
        r[i] = (hv[i] + fmaxf(v, 0.f)) * 0.5f;
    }
    *(uint4*)&hP[ob] = make_uint4(packsplit(r[0]), packsplit(r[1]), packsplit(r[2]), packsplit(r[3]));
}

static inline int gb64(long m) { return (int)((m + 63) / 64); }

extern "C" void kernel_launch(void* const* d_in, const int* in_sizes, int n_in,
                              void* d_out, int out_size, void* d_ws, size_t ws_size,
                              hipStream_t stream)
{
    const float* x         = (const float*)d_in[0];
    const int*   ei        = (const int*)  d_in[1];
    const float* edge_attr = (const float*)d_in[2];
    const float* node_w    = (const float*)d_in[3];
    const float* node_b    = (const float*)d_in[4];
    const float* edge_w    = (const float*)d_in[5];
    const float* edge_b    = (const float*)d_in[6];
    const float* lin_w     = (const float*)d_in[7];
    const float* lin_b     = (const float*)d_in[8];
    const float* w1        = (const float*)d_in[9];
    const float* b1        = (const float*)d_in[10];
    const float* w2        = (const float*)d_in[11];
    const float* b2        = (const float*)d_in[12];
    const float* gamma     = (const float*)d_in[13];
    const float* beta      = (const float*)d_in[14];
    const float* ew1       = (const float*)d_in[15];
    const float* eb1       = (const float*)d_in[16];
    const float* ew2       = (const float*)d_in[17];
    const float* eb2       = (const float*)d_in[18];
    const float* mw1       = (const float*)d_in[19];
    const float* mb1       = (const float*)d_in[20];
    const float* mw2       = (const float*)d_in[21];
    const float* mb2       = (const float*)d_in[22];
    const float* mw3       = (const float*)d_in[23];
    const float* mb3       = (const float*)d_in[24];
    float* out = (float*)d_out;

    // ---- workspace: [0,2MB) weights | [2MB,16MB) ints+stats | [16MB,..) activations
    ushort* pw = (ushort*)d_ws;
    size_t off_w = 0;
    ushort *nwH, *nwL, *ewH, *ewL, *liH, *liL, *w1H, *w1L, *w2H, *w2L,
           *wsH, *wsL, *wdH, *wdL, *weH, *weL, *e2H, *e2L,
           *msH, *msL, *mdH, *mdL, *meH, *meL, *m2H, *m2L;
    auto nextw = [&](size_t s, ushort*& H, ushort*& L) { H = pw + off_w; L = pw + off_w + s; off_w += 2 * s; };
    nextw(128 * 128,     nwH, nwL);   // node_w
    nextw(128 * 64,      ewH, ewL);   // edge_w
    nextw(2 * 128 * 128, liH, liL);   // lin_w x2
    nextw(2 * 128 * 128, w1H, w1L);
    nextw(2 * 128 * 128, w2H, w2L);
    nextw(2 * 128 * 128, wsH, wsL);   // ew1 rows 0-99   (W_s) x2
    nextw(2 * 128 * 128, wdH, wdL);   // ew1 rows 100-199 (W_d) x2
    nextw(2 * 128 * 128, weH, weL);   // ew1 rows 200-299 (W_e) x2
    nextw(2 * 128 * 128, e2H, e2L);   // ew2 x2
    nextw(64 * 128,      msH, msL);   // mw1 rows 0-99   (M_s)
    nextw(64 * 128,      mdH, mdL);   // mw1 rows 100-199 (M_d)
    nextw(64 * 128,      meH, meL);   // mw1 rows 200-299 (M_e)
    nextw(32 * 64,       m2H, m2L);   // mw2

    int* intb = (int*)((char*)d_ws + (2u << 20));
    int* cnt   = intb;
    int* coff  = cnt + N_NODES;
    int* pos   = coff + N_NODES + 1;
    int* eidx  = pos + N_NODES;
    int* psrc  = eidx + N_EDGES;
    int* pdst  = psrc + N_EDGES;
    float* stats = (float*)(pdst + N_EDGES);

    char* fbase = (char*)d_ws + (16u << 20);
    uint* eP  = (uint*)fbase;                          // E*112 words (358.4MB)
    uint* hP  = eP + (size_t)N_EDGES * LDP;            // N*112 (44.8MB)
    uint* zP  = hP + (size_t)N_NODES * LDP;            // N*112 (44.8MB)
    uint* PSD = zP + (size_t)N_NODES * LDP;            // N*224 (89.6MB)
    uint* QSD = PSD + (size_t)N_NODES * PSTR;          // N*128 (51.2MB)
    float* aggF = (float*)(QSD + (size_t)N_NODES * QSTR);  // N*104 fp32
    float* z2   = aggF + (size_t)N_NODES * TSTR;           // N*104 fp32

    const int* srcp = ei;
    const int* dstp = ei + N_EDGES;
    dim3 blk(256);

    auto packl = [&](const float* W, ushort* H, ushort* L, int K, int NC, int Kp, int NCp,
                     int batch, int krow0, int srcK) {
        int total = batch * NCp * Kp;
        pack_k<<<(total + 255) / 256, blk, 0, stream>>>(W, H, L, K, NC, Kp, NCp, total, krow0, srcK);
    };
    packl(node_w, nwH, nwL, 128, 100, 128, 128, 1, 0, 128);
    packl(edge_w, ewH, ewL,  64, 100,  64, 128, 1, 0, 64);
    packl(lin_w,  liH, liL, 100, 100, 128, 128, 2, 0, 100);
    packl(w1,     w1H, w1L, 100, 100, 128, 128, 2, 0, 100);
    packl(w2,     w2H, w2L, 100, 100, 128, 128, 2, 0, 100);
    packl(ew1,    wsH, wsL, 100, 100, 128, 128, 2, 0,   300);
    packl(ew1,    wdH, wdL, 100, 100, 128, 128, 2, 100, 300);
    packl(ew1,    weH, weL, 100, 100, 128, 128, 2, 200, 300);
    packl(ew2,    e2H, e2L, 100, 100, 128, 128, 2, 0, 100);
    packl(mw1,    msH, msL, 100,  50, 128,  64, 1, 0,   300);
    packl(mw1,    mdH, mdL, 100,  50, 128,  64, 1, 100, 300);
    packl(mw1,    meH, meL, 100,  50, 128,  64, 1, 200, 300);
    packl(mw2,    m2H, m2L,  50,  25,  64,  32, 1, 0, 50);

    hipMemsetAsync(cnt, 0, N_NODES * sizeof(int), stream);
    hist_k<<<(N_EDGES + 255) / 256, blk, 0, stream>>>(dstp, cnt);
    scan_k<<<1, dim3(1024), 0, stream>>>(cnt, coff);
    hipMemsetAsync(pos, 0, N_NODES * sizeof(int), stream);
    fill_k<<<(N_EDGES + 255) / 256, blk, 0, stream>>>(dstp, coff, pos, eidx);
    perm_k<<<(N_EDGES + 255) / 256, blk, 0, stream>>>(eidx, srcp, dstp, psrc, pdst);

    // 1. h = x @ node_w + node_b   (fp32 A, K=128) -> hP
    gemm10_k<8,2,4,0,0,1,0,0,0><<<gb64(N_NODES), blk, 0, stream>>>(
        nullptr, 0, x, 128, nwH, nwL, node_b, nullptr, hP, LDP, N_NODES, 100, nullptr);
    // 2. e[j] = edge_attr[eidx[j]] @ edge_w + edge_b -> eP
    gemm10_k<8,2,2,0,3,1,0,0,0><<<gb64(N_EDGES), blk, 0, stream>>>(
        nullptr, 0, edge_attr, 64, ewH, ewL, edge_b, nullptr, eP, LDP, N_EDGES, 100, eidx);

    float zerob[1]; (void)zerob;
    for (int i = 0; i < 2; ++i) {
        h2agg_k<<<(N_NODES * 26 + 255) / 256, blk, 0, stream>>>(hP, aggF);
        // 3+4+5. msg GEMM + gather-add + segmented aggregate
        msg_agg_k<<<gb64(N_EDGES), blk, 0, stream>>>(
            eP, liH + (size_t)i * 16384, liL + (size_t)i * 16384, lin_b + i * HDIM,
            hP, psrc, pdst, aggF);
        // 6. z = relu(aggF @ w1 + b1) -> zP
        gemm10_k<8,2,4,1,0,1,0,0,0><<<gb64(N_NODES), blk, 0, stream>>>(
            nullptr, 0, aggF, TSTR, w1H + (size_t)i * 16384, w1L + (size_t)i * 16384,
            b1 + i * HDIM, nullptr, zP, LDP, N_NODES, 100, nullptr);
        // 7. z2 = z @ w2 + b2 -> fp32
        gemm10_k<8,2,4,0,0,0,1,1,0><<<gb64(N_NODES), blk, 0, stream>>>(
            zP, LDP, nullptr, 0, w2H + (size_t)i * 16384, w2L + (size_t)i * 16384,
            b2 + i * HDIM, z2, nullptr, TSTR, N_NODES, 100, nullptr);
        // 8. BN stats
        hipMemsetAsync(stats, 0, 2 * HDIM * sizeof(float), stream);
        bn_stats_k<<<1024, dim3(128), 0, stream>>>(z2, stats);
        // 9. h = (h + relu(BN(z2)))/2
        bn_apply_k<<<(N_NODES * 25 + 255) / 256, blk, 0, stream>>>(
            z2, stats, gamma + i * HDIM, beta + i * HDIM, hP);
        // PSD = [h@Ws | h@Wd]  (node-level, bias=0 via stats buffer trick: use zeroed stats tail)
        hipMemsetAsync(stats + 2 * HDIM, 0, 128 * sizeof(float), stream);
        gemm10_k<8,2,4,0,0,0,0,1,0><<<gb64(N_NODES), blk, 0, stream>>>(
            hP, LDP, nullptr, 0, wsH + (size_t)i * 16384, wsL + (size_t)i * 16384,
            stats + 2 * HDIM, nullptr, PSD, PSTR, N_NODES, 100, nullptr);
        gemm10_k<8,2,4,0,0,0,0,1,0><<<gb64(N_NODES), blk, 0, stream>>>(
            hP, LDP, nullptr, 0, wdH + (size_t)i * 16384, wdL + (size_t)i * 16384,
            stats + 2 * HDIM, nullptr, PSD + 112, PSTR, N_NODES, 100, nullptr);
        // 10+11. fused edge update (sequential-e GEMM + coalesced PSD adds)
        fused_edge_k<<<gb64(N_EDGES), blk, 0, stream>>>(
            eP, PSD,
            weH + (size_t)i * 16384, weL + (size_t)i * 16384, eb1 + i * HDIM,
            e2H + (size_t)i * 16384, e2L + (size_t)i * 16384, eb2 + i * HDIM,
            psrc, pdst);
    }

    // QSD = [relu(h)@Ms | relu(h)@Md]
    hipMemsetAsync(stats + 2 * HDIM, 0, 128 * sizeof(float), stream);
    gemm10_k<4,1,4,0,0,0,0,1,1><<<gb64(N_NODES), blk, 0, stream>>>(
        hP, LDP, nullptr, 0, msH, msL, stats + 2 * HDIM, nullptr, QSD, QSTR, N_NODES, 50, nullptr);
    gemm10_k<4,1,4,0,0,0,0,1,1><<<gb64(N_NODES), blk, 0, stream>>>(
        hP, LDP, nullptr, 0, mdH, mdL, stats + 2 * HDIM, nullptr, QSD + 64, QSTR, N_NODES, 50, nullptr);

    // 12+13+14. fused final MLP -> out[eidx]
    fused_final_k<<<gb64(N_EDGES), blk, 0, stream>>>(
        eP, QSD, meH, meL, mb1, m2H, m2L, mb2, mw3, mb3, psrc, pdst, eidx, out);
}